// Round 11
// baseline (433.046 us; speedup 1.0000x reference)
//
#include <hip/hip_runtime.h>
#include <hip/hip_cooperative_groups.h>
#include <cstdint>
#include <cstddef>

namespace cg = cooperative_groups;

#define N_NODES   100000
#define N_EDGES   1600000
#define D_IN      128
#define HIDDEN    64
#define N_GRAPHS  512
#define N_CLASSES 10

#define NB   196          // buckets (dst>>9), 512 nodes each; 99999>>9 = 195
#define EB   1563         // hist edge-blocks, 1024 edges each
#define EB4  391          // scatter blocks, 4096 edges each (4 hist-blocks)
#define NBE  (NB * EB)    // 306,348 count-matrix entries
#define SCB  75           // scan blocks over NBE (4096 each)
#define BCAP 12288        // per-bucket LDS srcs capacity (avg 8163, std ~90)
#define PSLOTS 8          // graphs spanned per 32-node gather block (avg ~1.2)

typedef __attribute__((ext_vector_type(8))) short bf16x8;
typedef __attribute__((ext_vector_type(4))) float f32x4;
typedef __attribute__((ext_vector_type(2))) float f32x2;

// ---- bf16 helpers ----
__device__ inline float bf2f(unsigned short u) {
    return __uint_as_float(((unsigned int)u) << 16);
}
__device__ inline unsigned short f2bf(float f) {
    unsigned int x = __float_as_uint(f);
    return (unsigned short)((x + 0x7FFF + ((x >> 16) & 1)) >> 16);
}

// ===========================================================================
// csr_build: COOPERATIVE kernel fusing hist -> scan1 -> scan3b -> scatterA2
// -> passB with grid.sync() between phases. 391 blocks x 256 threads,
// 54.3 KB LDS (3 blocks/CU co-residency >= 391). Same algorithms/traffic as
// the 5 separate kernels (proven at 230-231 us); saves 4 dispatch gaps.
// ===========================================================================
__global__ __launch_bounds__(256)
void csr_build_kernel(const int* __restrict__ src, const int* __restrict__ dst,
                      int* __restrict__ HA, int* __restrict__ bsum,
                      int* __restrict__ posA, unsigned int* __restrict__ edgeA,
                      int* __restrict__ noffs, float* __restrict__ dinv,
                      int* __restrict__ srcs2) {
    cg::grid_group grid = cg::this_grid();
    __shared__ int hist[512];
    __shared__ int off[512];
    __shared__ int ps[256];
    __shared__ int srcs_l[BCAP];

    const int tid = threadIdx.x;
    const int blk = blockIdx.x;

    // ---- phase 1: bucket histogram, grid-stride over EB virtual blocks ----
    for (int hb = blk; hb < EB; hb += gridDim.x) {
        for (int i = tid; i < NB; i += 256) hist[i] = 0;
        __syncthreads();
        int base = hb * 1024 + tid;
#pragma unroll
        for (int j = 0; j < 4; j++) {
            int t = base + j * 256;
            if (t < N_EDGES) atomicAdd(&hist[dst[t] >> 9], 1);
        }
        __syncthreads();
        for (int b = tid; b < NB; b += 256) HA[b * EB + hb] = hist[b];
        __syncthreads();
    }
    grid.sync();

    // ---- phase 2: per-4096 block sums of HA ----
    if (blk < SCB) {
        int base = blk * 4096 + tid * 16;
        int s = 0;
#pragma unroll
        for (int j = 0; j < 16; j++) { int i = base + j; if (i < NBE) s += HA[i]; }
        ps[tid] = s; __syncthreads();
        for (int o = 128; o > 0; o >>= 1) {
            if (tid < o) ps[tid] += ps[tid + o];
            __syncthreads();
        }
        if (tid == 0) bsum[blk] = ps[0];
    }
    grid.sync();

    // ---- phase 3: inline block-sum scan + element scan -> posA ----
    if (blk < SCB) {
        int bv = (tid < SCB) ? bsum[tid] : 0;
        hist[tid] = bv; __syncthreads();
        for (int o = 1; o < 256; o <<= 1) {
            int t = (tid >= o) ? hist[tid - o] : 0;
            __syncthreads();
            hist[tid] += t;
            __syncthreads();
        }
        hist[tid] -= bv;   // exclusive block offsets
        __syncthreads();
        int blockoff = hist[blk];

        int base = blk * 4096 + tid * 16;
        int v[16]; int s = 0;
#pragma unroll
        for (int j = 0; j < 16; j++) {
            int i = base + j;
            v[j] = (i < NBE) ? HA[i] : 0;
            s += v[j];
        }
        ps[tid] = s; __syncthreads();
        for (int o = 1; o < 256; o <<= 1) {
            int t = (tid >= o) ? ps[tid - o] : 0;
            __syncthreads();
            ps[tid] += t;
            __syncthreads();
        }
        int ex = ps[tid] - s + blockoff;
#pragma unroll
        for (int j = 0; j < 16; j++) {
            int i = base + j;
            if (i < NBE) { posA[i] = ex; ex += v[j]; }
        }
        if (blk == 0 && tid == 0) posA[NBE] = N_EDGES;
    }
    grid.sync();

    // ---- phase 4: bucket-sort edges (LDS cursors, packed u32) ----
    {
        for (int b = tid; b < NB; b += 256) off[b] = posA[b * EB + blk * 4];
        __syncthreads();
        int base = blk * 4096 + tid;
#pragma unroll
        for (int j = 0; j < 16; j++) {
            int t = base + j * 256;
            if (t < N_EDGES) {
                int d = dst[t];
                unsigned int pk = (((unsigned int)(d & 511)) << 17) | (unsigned int)src[t];
                int r = atomicAdd(&off[d >> 9], 1);
                edgeA[r] = pk;
            }
        }
    }
    grid.sync();

    // ---- phase 5: per-bucket CSR build (196 blocks active) ----
    if (blk < NB) {
        int e0 = posA[blk * EB];
        int e1 = posA[(blk + 1) * EB];
        int n0 = blk << 9;
        int nn = min(512, N_NODES - n0);
        int len = e1 - e0;

        __syncthreads();
        hist[tid] = 0; hist[tid + 256] = 0;
        __syncthreads();
        for (int i = e0 + tid; i < e1; i += 256) atomicAdd(&hist[edgeA[i] >> 17], 1);
        __syncthreads();

        for (int n = tid; n < nn; n += 256) dinv[n0 + n] = rsqrtf((float)hist[n] + 1.0f);

        int a0 = hist[2 * tid], a1 = hist[2 * tid + 1];
        ps[tid] = a0 + a1;
        __syncthreads();
        for (int d = 1; d < 256; d <<= 1) {
            int v = (tid >= d) ? ps[tid - d] : 0;
            __syncthreads();
            ps[tid] += v;
            __syncthreads();
        }
        int pre = ps[tid] - (a0 + a1);
        off[2 * tid] = pre;
        off[2 * tid + 1] = pre + a0;
        __syncthreads();

        for (int n = tid; n < nn; n += 256) noffs[n0 + n] = e0 + off[n];
        if (blk == NB - 1 && tid == 0) noffs[N_NODES] = N_EDGES;
        __syncthreads();

        if (len <= BCAP) {
            for (int i = e0 + tid; i < e1; i += 256) {
                unsigned int e = edgeA[i];
                int r = atomicAdd(&off[e >> 17], 1);
                srcs_l[r] = (int)(e & 0x1FFFFu);
            }
            __syncthreads();
            for (int i = tid; i < len; i += 256) srcs2[e0 + i] = srcs_l[i];
        } else {
            for (int i = e0 + tid; i < e1; i += 256) {
                unsigned int e = edgeA[i];
                int r = atomicAdd(&off[e >> 17], 1);
                srcs2[e0 + r] = (int)(e & 0x1FFFFu);
            }
        }
    }
}

// ===========================================================================
// gemm1: x fp32 @ W1 -> bf16, A-fragments loaded DIRECTLY from global
// (no As LDS staging), epilogue scales by dinv[row] (pre-scaled h1 table).
// 512 threads, 128 rows/block. LDS = Wt only (17.4 KB).
// ===========================================================================
__global__ __launch_bounds__(512)
void gemm1_kernel(const float* __restrict__ X, const float* __restrict__ W,
                  const float* __restrict__ dinv, unsigned short* __restrict__ H,
                  int n_rows) {
    constexpr int K  = D_IN;
    constexpr int KP = K + 8;
    __shared__ unsigned short Wt[64 * KP];

    const int tid  = threadIdx.x;
    const int row0 = blockIdx.x * 128;

    for (int i = tid; i < K * 64; i += 512) {
        int k = i >> 6;
        int n = i & 63;
        Wt[n * KP + k] = f2bf(W[i]);
    }

    const int wave = tid >> 6;
    const int lane = tid & 63;
    const int lrow = lane & 15;
    const int quad = lane >> 4;
    const int m = wave * 16 + lrow;
    const int row = row0 + m;
    const bool valid = row < n_rows;

    // issue all 8 A-chunk loads up front (full MLP)
    float4 xa[8];
    if (valid) {
        const float4* xr4 = (const float4*)(X + (size_t)row * K);
#pragma unroll
        for (int kt = 0; kt < 4; kt++) {
            int q = (kt * 32 + quad * 8) >> 2;
            xa[2 * kt]     = xr4[q];
            xa[2 * kt + 1] = xr4[q + 1];
        }
    } else {
#pragma unroll
        for (int j = 0; j < 8; j++) xa[j] = make_float4(0.f, 0.f, 0.f, 0.f);
    }
    __syncthreads();

    f32x4 acc0 = {0.f, 0.f, 0.f, 0.f};
    f32x4 acc1 = {0.f, 0.f, 0.f, 0.f};
    f32x4 acc2 = {0.f, 0.f, 0.f, 0.f};
    f32x4 acc3 = {0.f, 0.f, 0.f, 0.f};

#pragma unroll
    for (int kt = 0; kt < 4; kt++) {
        int k0 = kt * 32 + quad * 8;
        const float* f = (const float*)&xa[2 * kt];
        bf16x8 a;
#pragma unroll
        for (int j = 0; j < 8; j++) a[j] = (short)f2bf(f[j]);
        bf16x8 b0 = *(const bf16x8*)&Wt[(0 * 16 + lrow) * KP + k0];
        bf16x8 b1 = *(const bf16x8*)&Wt[(1 * 16 + lrow) * KP + k0];
        bf16x8 b2 = *(const bf16x8*)&Wt[(2 * 16 + lrow) * KP + k0];
        bf16x8 b3 = *(const bf16x8*)&Wt[(3 * 16 + lrow) * KP + k0];
        acc0 = __builtin_amdgcn_mfma_f32_16x16x32_bf16(a, b0, acc0, 0, 0, 0);
        acc1 = __builtin_amdgcn_mfma_f32_16x16x32_bf16(a, b1, acc1, 0, 0, 0);
        acc2 = __builtin_amdgcn_mfma_f32_16x16x32_bf16(a, b2, acc2, 0, 0, 0);
        acc3 = __builtin_amdgcn_mfma_f32_16x16x32_bf16(a, b3, acc3, 0, 0, 0);
    }

    f32x4 accs[4] = {acc0, acc1, acc2, acc3};
#pragma unroll
    for (int r = 0; r < 4; r++) {
        int orow = row0 + wave * 16 + quad * 4 + r;
        if (orow < n_rows) {
            float dv = dinv[orow];
#pragma unroll
            for (int c = 0; c < 4; c++)
                H[(size_t)orow * 64 + c * 16 + lrow] = f2bf(accs[c][r] * dv);
        }
    }
}

// ---- unpack-add helpers (tables are pre-scaled by dinv[src]) ----
__device__ inline void upk_add(int4 u, float* acc) {
    unsigned int a = (unsigned int)u.x, b = (unsigned int)u.y;
    unsigned int d = (unsigned int)u.z, e = (unsigned int)u.w;
    acc[0] += __uint_as_float(a << 16);
    acc[1] += __uint_as_float(a & 0xFFFF0000u);
    acc[2] += __uint_as_float(b << 16);
    acc[3] += __uint_as_float(b & 0xFFFF0000u);
    acc[4] += __uint_as_float(d << 16);
    acc[5] += __uint_as_float(d & 0xFFFF0000u);
    acc[6] += __uint_as_float(e << 16);
    acc[7] += __uint_as_float(e & 0xFFFF0000u);
}

__device__ inline void upk8_add(int2 u, float* acc) {
    f32x2 p0 = __builtin_amdgcn_cvt_pk_f32_fp8(u.x, false);
    f32x2 p1 = __builtin_amdgcn_cvt_pk_f32_fp8(u.x, true);
    f32x2 p2 = __builtin_amdgcn_cvt_pk_f32_fp8(u.y, false);
    f32x2 p3 = __builtin_amdgcn_cvt_pk_f32_fp8(u.y, true);
    acc[0] += p0.x; acc[1] += p0.y;
    acc[2] += p1.x; acc[3] += p1.y;
    acc[4] += p2.x; acc[5] += p2.y;
    acc[6] += p3.x; acc[7] += p3.y;
}

// ===========================================================================
// FUSED gather1 + gemm2: 512 threads, 64 nodes/block, NATURAL node order.
// Phase A: 8 lanes/node aggregate pre-scaled bf16 rows (8-deep batches with
// cross-batch src prefetch), dn*acc + b1, relu, bf16 row to LDS.
// Phase B: 8 waves MFMA 64x64x64, epilogue scales by dinv[row], stores fp8.
// ===========================================================================
__global__ __launch_bounds__(512)
void gather1_gemm2_kernel(const int* __restrict__ offs, const int* __restrict__ srcs,
                          const float* __restrict__ dinv, const unsigned short* __restrict__ h,
                          const float* __restrict__ b1v, const float* __restrict__ W2,
                          unsigned char* __restrict__ H8, int n_nodes) {
    constexpr int KP = 72;
    __shared__ unsigned short Hs[64 * KP];
    __shared__ unsigned short Wt[64 * KP];

    const int tid   = threadIdx.x;
    const int node0 = blockIdx.x * 64;

    // stage W2^T as bf16 (W2 is [64][64] row-major, in x out)
    for (int i = tid; i < 64 * 64; i += 512) {
        int k = i >> 6;
        int n = i & 63;
        Wt[n * KP + k] = f2bf(W2[i]);
    }

    // ---- phase A: gather-aggregate, 8-deep ----
    const int g    = tid >> 3;
    const int node = node0 + g;
    const int cg   = (tid & 7) * 8;

    float acc[8];
#pragma unroll
    for (int j = 0; j < 8; j++) acc[j] = 0.f;
    float dn = 0.f;

    if (node < n_nodes) {
        dn = dinv[node];
        int4 us = *(const int4*)(h + (size_t)node * 64 + cg);  // self row (pre-scaled)
        upk_add(us, acc);

        int i = offs[node];
        const int i1 = offs[node + 1];
        int rem = i1 - i;
        if (rem > 0) {
            int s[8];
#pragma unroll
            for (int j = 0; j < 8; j++) s[j] = srcs[i + (j < rem ? j : rem - 1)];
            while (rem > 0) {
                int4 u8[8];
#pragma unroll
                for (int j = 0; j < 8; j++)
                    u8[j] = *(const int4*)(h + (size_t)s[j] * 64 + cg);
                const int cur  = rem < 8 ? rem : 8;
                const int ni   = i + cur;
                const int nrem = rem - cur;
                if (nrem > 0) {
#pragma unroll
                    for (int j = 0; j < 8; j++)
                        s[j] = srcs[ni + (j < nrem ? j : nrem - 1)];
                }
#pragma unroll
                for (int j = 0; j < 8; j++) { if (j < cur) upk_add(u8[j], acc); }
                i = ni; rem = nrem;
            }
        }
    }

    // bias + relu + write LDS row (invalid nodes write relu(b1): rows unused)
    {
        float4 bv0 = *(const float4*)(b1v + cg);
        float4 bv1 = *(const float4*)(b1v + cg + 4);
        float r0 = fmaxf(dn * acc[0] + bv0.x, 0.f);
        float r1 = fmaxf(dn * acc[1] + bv0.y, 0.f);
        float r2 = fmaxf(dn * acc[2] + bv0.z, 0.f);
        float r3 = fmaxf(dn * acc[3] + bv0.w, 0.f);
        float r4 = fmaxf(dn * acc[4] + bv1.x, 0.f);
        float r5 = fmaxf(dn * acc[5] + bv1.y, 0.f);
        float r6 = fmaxf(dn * acc[6] + bv1.z, 0.f);
        float r7 = fmaxf(dn * acc[7] + bv1.w, 0.f);
        ushort4 p0 = make_ushort4(f2bf(r0), f2bf(r1), f2bf(r2), f2bf(r3));
        ushort4 p1 = make_ushort4(f2bf(r4), f2bf(r5), f2bf(r6), f2bf(r7));
        *(ushort4*)&Hs[g * KP + cg]     = p0;
        *(ushort4*)&Hs[g * KP + cg + 4] = p1;
    }
    __syncthreads();

    // ---- phase B: MFMA 64x64x64, 8 waves ----
    const int wave = tid >> 6;
    const int lane = tid & 63;
    const int lrow = lane & 15;
    const int quad = lane >> 4;
    const int rt = (wave & 3) * 16;   // row tile
    const int ct = (wave >> 2) * 32;  // col tile
    const int m = rt + lrow;

    f32x4 acc0 = {0.f, 0.f, 0.f, 0.f};
    f32x4 acc1 = {0.f, 0.f, 0.f, 0.f};
#pragma unroll
    for (int kt = 0; kt < 2; kt++) {
        int k0 = kt * 32 + quad * 8;
        bf16x8 a  = *(const bf16x8*)&Hs[m * KP + k0];
        bf16x8 w0 = *(const bf16x8*)&Wt[(ct + lrow) * KP + k0];
        bf16x8 w1 = *(const bf16x8*)&Wt[(ct + 16 + lrow) * KP + k0];
        acc0 = __builtin_amdgcn_mfma_f32_16x16x32_bf16(a, w0, acc0, 0, 0, 0);
        acc1 = __builtin_amdgcn_mfma_f32_16x16x32_bf16(a, w1, acc1, 0, 0, 0);
    }

    f32x4 accs[2] = {acc0, acc1};
#pragma unroll
    for (int r = 0; r < 4; r++) {
        int row = node0 + rt + quad * 4 + r;
        if (row < n_nodes) {
            float dv = dinv[row];
#pragma unroll
            for (int c = 0; c < 2; c++) {
                float v = accs[c][r] * dv;   // fold layer-2 dinv[src] into table
                int p = __builtin_amdgcn_cvt_pk_fp8_f32(v, v, 0, false);
                H8[(size_t)row * 64 + ct + c * 16 + lrow] = (unsigned char)(p & 0xFF);
            }
        }
    }
}

// ===========================================================================
// Gather B + POOL fused (layer 2): fp8 table PRE-SCALED by dinv[src].
// 8 lanes/node x int2, 32 nodes/block (800K threads). PING-PONG double
// buffer (measured equal to plain 8-deep; kept from r9's verified source).
// ===========================================================================
__global__ __launch_bounds__(256)
void gather_fp8_pool_kernel(const int* __restrict__ offs, const int* __restrict__ srcs,
                            const float* __restrict__ dinv, const unsigned char* __restrict__ h8,
                            const float* __restrict__ b, const int* __restrict__ batch,
                            float* __restrict__ pooled, float* __restrict__ cnt,
                            int n_nodes) {
    __shared__ float pacc[PSLOTS][64];
    __shared__ float lcnt[PSLOTS];
    __shared__ int sg[2];

    int tid = threadIdx.x;
    int node0 = blockIdx.x * 32;
    int lastn = min(node0 + 31, n_nodes - 1);
    for (int i = tid; i < PSLOTS * 64; i += 256) ((float*)pacc)[i] = 0.f;
    if (tid < PSLOTS) lcnt[tid] = 0.f;
    if (tid == 0) { sg[0] = batch[min(node0, n_nodes - 1)]; sg[1] = batch[lastn]; }
    __syncthreads();
    int g0 = sg[0];
    bool single = (sg[0] == sg[1]);   // block-uniform

    int node = node0 + (tid >> 3);
    int cg = (tid & 7) * 8;

    float r[8];
#pragma unroll
    for (int j = 0; j < 8; j++) r[j] = 0.f;

    if (node < n_nodes) {
        float dn = dinv[node];
        float acc[8];
#pragma unroll
        for (int j = 0; j < 8; j++) acc[j] = 0.f;
        {
            int2 u = *(const int2*)(h8 + (size_t)node * 64 + cg);  // self (pre-scaled)
            upk8_add(u, acc);
        }

        int i = offs[node];
        const int i1 = offs[node + 1];
        int rem = i1 - i;

        int curA = 0;
        int2 uA[8];
        if (rem > 0) {
            curA = rem < 8 ? rem : 8;
            int sA[8];
#pragma unroll
            for (int j = 0; j < 8; j++) sA[j] = srcs[i + (j < curA ? j : curA - 1)];
#pragma unroll
            for (int j = 0; j < 8; j++)
                uA[j] = *(const int2*)(h8 + (size_t)sA[j] * 64 + cg);
            i += curA; rem -= curA;
        }
        while (curA > 0) {
            int curB = 0;
            int2 uB[8];
            if (rem > 0) {
                curB = rem < 8 ? rem : 8;
                int sB[8];
#pragma unroll
                for (int j = 0; j < 8; j++) sB[j] = srcs[i + (j < curB ? j : curB - 1)];
#pragma unroll
                for (int j = 0; j < 8; j++)
                    uB[j] = *(const int2*)(h8 + (size_t)sB[j] * 64 + cg);
                i += curB; rem -= curB;
            }
            // consume A (only waits for A's 8 loads; B's stay in flight)
#pragma unroll
            for (int j = 0; j < 8; j++) { if (j < curA) upk8_add(uA[j], acc); }
#pragma unroll
            for (int j = 0; j < 8; j++) uA[j] = uB[j];
            curA = curB;
        }

        float4 b0 = *(const float4*)(b + cg);
        float4 b1 = *(const float4*)(b + cg + 4);
        r[0] = fmaxf(dn * acc[0] + b0.x, 0.f);
        r[1] = fmaxf(dn * acc[1] + b0.y, 0.f);
        r[2] = fmaxf(dn * acc[2] + b0.z, 0.f);
        r[3] = fmaxf(dn * acc[3] + b0.w, 0.f);
        r[4] = fmaxf(dn * acc[4] + b1.x, 0.f);
        r[5] = fmaxf(dn * acc[5] + b1.y, 0.f);
        r[6] = fmaxf(dn * acc[6] + b1.z, 0.f);
        r[7] = fmaxf(dn * acc[7] + b1.w, 0.f);
    }

    if (single) {
        // butterfly over lanes ^8,^16,^32: sums the 8 nodes of this wave
#pragma unroll
        for (int j = 0; j < 8; j++) {
            float v = r[j];
            v += __shfl_xor(v, 8);
            v += __shfl_xor(v, 16);
            v += __shfl_xor(v, 32);
            r[j] = v;
        }
        int wave = tid >> 6;
        int lane = tid & 63;
        if (lane < 8) {
#pragma unroll
            for (int j = 0; j < 8; j++) pacc[wave][lane * 8 + j] = r[j];
        }
        __syncthreads();
        if (tid < 64) {
            float s = pacc[0][tid] + pacc[1][tid] + pacc[2][tid] + pacc[3][tid];
            if (s != 0.f) unsafeAtomicAdd(&pooled[(size_t)g0 * 64 + tid], s);
        }
        if (tid == 0) {
            int valid = min(32, n_nodes - node0);
            unsafeAtomicAdd(&cnt[g0], (float)valid);
        }
    } else {
        if (node < n_nodes) {
            int g = batch[node];
            int slot = g - g0;          // batch sorted -> slot >= 0
            if (slot < PSLOTS) {
#pragma unroll
                for (int j = 0; j < 8; j++) atomicAdd(&pacc[slot][cg + j], r[j]);
                if ((tid & 7) == 0) atomicAdd(&lcnt[slot], 1.f);
            } else {
#pragma unroll
                for (int j = 0; j < 8; j++) unsafeAtomicAdd(&pooled[(size_t)g * 64 + cg + j], r[j]);
                if ((tid & 7) == 0) unsafeAtomicAdd(&cnt[g], 1.f);
            }
        }
        __syncthreads();
        for (int i = tid; i < PSLOTS * 64; i += 256) {
            float v = ((float*)pacc)[i];
            if (v != 0.f) unsafeAtomicAdd(&pooled[(size_t)(g0 + (i >> 6)) * 64 + (i & 63)], v);
        }
        if (tid < PSLOTS && lcnt[tid] != 0.f) unsafeAtomicAdd(&cnt[g0 + tid], lcnt[tid]);
    }
}

// ===========================================================================
// Head: pooled mean -> logits -> log_softmax.
// ===========================================================================
__global__ __launch_bounds__(256)
void head_kernel(const float* __restrict__ pooled, const float* __restrict__ cnt,
                 const float* __restrict__ Wfc, const float* __restrict__ bfc,
                 float* __restrict__ out) {
    __shared__ float Ws[HIDDEN * N_CLASSES];
    __shared__ float bs[N_CLASSES];
    int tid = threadIdx.x;
    for (int i = tid; i < HIDDEN * N_CLASSES; i += 256) Ws[i] = Wfc[i];
    if (tid < N_CLASSES) bs[tid] = bfc[tid];
    __syncthreads();

    int g = blockIdx.x * 256 + tid;
    if (g >= N_GRAPHS) return;

    float inv = 1.f / fmaxf(cnt[g], 1.f);
    float p[HIDDEN];
#pragma unroll
    for (int k = 0; k < HIDDEN; k++) p[k] = pooled[(size_t)g * 64 + k] * inv;

    float lg[N_CLASSES];
    float m = -1e30f;
#pragma unroll
    for (int j = 0; j < N_CLASSES; j++) {
        float a = bs[j];
#pragma unroll
        for (int k = 0; k < HIDDEN; k++) a += p[k] * Ws[k * N_CLASSES + j];
        lg[j] = a;
        m = fmaxf(m, a);
    }
    float s = 0.f;
#pragma unroll
    for (int j = 0; j < N_CLASSES; j++) s += __expf(lg[j] - m);
    float lse = m + __logf(s);
#pragma unroll
    for (int j = 0; j < N_CLASSES; j++) out[(size_t)g * N_CLASSES + j] = lg[j] - lse;
}

// ===========================================================================
// Launch
// ===========================================================================
extern "C" void kernel_launch(void* const* d_in, const int* in_sizes, int n_in,
                              void* d_out, int out_size, void* d_ws, size_t ws_size,
                              hipStream_t stream) {
    const float* x   = (const float*)d_in[0];
    const int*   ei  = (const int*)d_in[1];
    const int*   bat = (const int*)d_in[2];
    const float* W1  = (const float*)d_in[3];
    const float* b1  = (const float*)d_in[4];
    const float* W2  = (const float*)d_in[5];
    const float* b2  = (const float*)d_in[6];
    const float* Wfc = (const float*)d_in[7];
    const float* bfc = (const float*)d_in[8];
    float* out = (float*)d_out;

    const int* src = ei;
    const int* dst = ei + N_EDGES;

    char* ws = (char*)d_ws;

    // Layout, total ~53.8 MB:
    const size_t OFF_H     = 0;          // h1 bf16 12.8 MB (pre-scaled by dinv in gemm1)
    const size_t OFF_SRCS2 = 12800000;   // node-major srcs 6.4 MB
    const size_t OFF_NOFFS = 19200000;   // 400,016
    const size_t OFF_DINV  = 19600016;   // 400,000
    const size_t OFF_BUFB  = 25600000;   // h2 fp8 6.4 MB (pre-scaled by dinv)
    const size_t OFF_EDGEA = 38400000;   // 6.4 MB packed u32 {ldst:9|src:17} (build only)
    const size_t OFF_HA    = 51200000;   // 1,225,392
    const size_t OFF_POSA  = 52425392;   // 1,225,396 (NBE+1 ints)
    const size_t OFF_BSUM  = 53650800;   // 1,024
    const size_t OFF_POOL  = 53651824;   // 131,072
    const size_t OFF_CNT   = 53782896;   // 2,048

    unsigned short* hbuf  = (unsigned short*)(ws + OFF_H);
    int*   srcs2  = (int*)  (ws + OFF_SRCS2);
    int*   noffs  = (int*)  (ws + OFF_NOFFS);
    float* dinv   = (float*)(ws + OFF_DINV);
    unsigned char* hbuf8 = (unsigned char*)(ws + OFF_BUFB);
    unsigned int* edgeA = (unsigned int*)(ws + OFF_EDGEA);
    int*   HA     = (int*)  (ws + OFF_HA);
    int*   posA   = (int*)  (ws + OFF_POSA);
    int*   bsum   = (int*)  (ws + OFF_BSUM);
    float* pooled = (float*)(ws + OFF_POOL);
    float* cnt    = (float*)(ws + OFF_CNT);

    const int GATHER_BLOCKS = (N_NODES * 8 + 255) / 256;  // 3125 (32 nodes/block)
    const int GEMM2_BLOCKS = (N_NODES + 63) / 64;         // 1563
    const int GEMM1_BLOCKS = (N_NODES + 127) / 128;       // 782

    hipMemsetAsync(pooled, 0, (size_t)(131072 + 2048), stream);

    // 1. fused CSR build: hist -> scan -> scatter -> passB, ONE cooperative
    //    launch (391 blocks, 54.3 KB LDS, 3 blocks/CU co-residency >= 391).
    {
        void* args[] = { (void*)&src, (void*)&dst, (void*)&HA, (void*)&bsum,
                         (void*)&posA, (void*)&edgeA, (void*)&noffs,
                         (void*)&dinv, (void*)&srcs2 };
        hipLaunchCooperativeKernel((void*)csr_build_kernel, dim3(EB4), dim3(256),
                                   args, 0, stream);
    }
    // 2. gemm1 (direct-global A, dinv-scaled epilogue): x @ W1 -> h1 bf16
    gemm1_kernel<<<GEMM1_BLOCKS, 512, 0, stream>>>(x, W1, dinv, hbuf, N_NODES);
    // 3. fused gather1 + gemm2: scaled h1 table -> h2 fp8 (pre-scaled)
    gather1_gemm2_kernel<<<GEMM2_BLOCKS, 512, 0, stream>>>(
        noffs, srcs2, dinv, hbuf, b1, W2, hbuf8, N_NODES);
    // 4. gather2 + pool fused (8 lanes/node, int2, ping-pong)
    gather_fp8_pool_kernel<<<GATHER_BLOCKS, 256, 0, stream>>>(
        noffs, srcs2, dinv, hbuf8, b2, bat, pooled, cnt, N_NODES);
    // 5. head
    head_kernel<<<(N_GRAPHS + 255) / 256, 256, 0, stream>>>(pooled, cnt, Wfc, bfc, out);
}

// Round 12
// 229.506 us; speedup vs baseline: 1.8869x; 1.8869x over previous
//
#include <hip/hip_runtime.h>
#include <cstdint>
#include <cstddef>

#define N_NODES   100000
#define N_EDGES   1600000
#define D_IN      128
#define HIDDEN    64
#define N_GRAPHS  512
#define N_CLASSES 10

#define NB   196          // buckets (dst>>9), 512 nodes each; 99999>>9 = 195
#define EB   1563         // hist edge-blocks, 1024 edges each
#define EB4  391          // scatter blocks, 4096 edges each (4 hist-blocks)
#define NBE  (NB * EB)    // 306,348 count-matrix entries
#define SCB  75           // scan blocks over NBE (4096 each)
#define BCAP 12288        // per-bucket LDS srcs capacity (avg 8163, std ~90)
#define PSLOTS 8          // graphs spanned per 32-node gather block (avg ~1.2)

typedef __attribute__((ext_vector_type(8))) short bf16x8;
typedef __attribute__((ext_vector_type(4))) float f32x4;
typedef __attribute__((ext_vector_type(2))) float f32x2;

// ---- bf16 helpers ----
__device__ inline float bf2f(unsigned short u) {
    return __uint_as_float(((unsigned int)u) << 16);
}
__device__ inline unsigned short f2bf(float f) {
    unsigned int x = __float_as_uint(f);
    return (unsigned short)((x + 0x7FFF + ((x >> 16) & 1)) >> 16);
}

// ===========================================================================
// scan1: per-4096 block sums of HA.
// ===========================================================================
__global__ __launch_bounds__(256)
void scan1_kernel(const int* __restrict__ in, int* __restrict__ bsum, int n) {
    __shared__ int lds[256];
    int tid = threadIdx.x;
    int base = blockIdx.x * 4096 + tid * 16;
    int s = 0;
#pragma unroll
    for (int j = 0; j < 16; j++) { int i = base + j; if (i < n) s += in[i]; }
    lds[tid] = s; __syncthreads();
    for (int off = 128; off > 0; off >>= 1) {
        if (tid < off) lds[tid] += lds[tid + off];
        __syncthreads();
    }
    if (tid == 0) bsum[blockIdx.x] = lds[0];
}

// ===========================================================================
// scan3b: inlines the block-sum scan (nb<=256 raw sums) + element scan.
// Writes posA; posA[n] (grand total) is the constant N_EDGES.
// (Harness-verified in round 10's passing run.)
// ===========================================================================
__global__ __launch_bounds__(256)
void scan3b_kernel(const int* __restrict__ in, const int* __restrict__ bsum,
                   int* __restrict__ out, int n, int nb) {
    __shared__ int bscan[256];
    __shared__ int lds[256];
    int tid = threadIdx.x;
    int bv = (tid < nb) ? bsum[tid] : 0;
    bscan[tid] = bv; __syncthreads();
    for (int off = 1; off < 256; off <<= 1) {
        int t = (tid >= off) ? bscan[tid - off] : 0;
        __syncthreads();
        bscan[tid] += t;
        __syncthreads();
    }
    bscan[tid] -= bv;                       // exclusive block offsets
    __syncthreads();
    int blockoff = bscan[blockIdx.x];

    int base = blockIdx.x * 4096 + tid * 16;
    int v[16]; int s = 0;
#pragma unroll
    for (int j = 0; j < 16; j++) {
        int i = base + j;
        v[j] = (i < n) ? in[i] : 0;
        s += v[j];
    }
    lds[tid] = s; __syncthreads();
    for (int off = 1; off < 256; off <<= 1) {
        int t = (tid >= off) ? lds[tid - off] : 0;
        __syncthreads();
        lds[tid] += t;
        __syncthreads();
    }
    int ex = lds[tid] - s + blockoff;
#pragma unroll
    for (int j = 0; j < 16; j++) {
        int i = base + j;
        if (i < n) { out[i] = ex; ex += v[j]; }
    }
    if (blockIdx.x == 0 && tid == 0) out[n] = N_EDGES;
}

// ===========================================================================
// hist: bucket histogram via LDS atomics. HA layout: [bucket][edge_block].
// ===========================================================================
__global__ __launch_bounds__(256)
void hist_kernel(const int* __restrict__ dst, int* __restrict__ HA) {
    __shared__ int cnt[NB];
    const int tid = threadIdx.x;
    const int hb = blockIdx.x;
    for (int i = tid; i < NB; i += 256) cnt[i] = 0;
    __syncthreads();
    int base = hb * 1024 + tid;
#pragma unroll
    for (int j = 0; j < 4; j++) {
        int t = base + j * 256;
        if (t < N_EDGES) atomicAdd(&cnt[dst[t] >> 9], 1);
    }
    __syncthreads();
    for (int b = tid; b < NB; b += 256) HA[b * EB + hb] = cnt[b];
}

// ===========================================================================
// scatterA2: bucket-sort edges, 4096 edges/block, PACKED u32 {ldst:9,src:17}.
// ===========================================================================
__global__ __launch_bounds__(256)
void scatterA2_kernel(const int* __restrict__ src, const int* __restrict__ dst,
                      const int* __restrict__ posA, unsigned int* __restrict__ edgeA) {
    __shared__ int off[NB];
    int tid = threadIdx.x, blk = blockIdx.x;
    for (int b = tid; b < NB; b += 256) off[b] = posA[b * EB + blk * 4];
    __syncthreads();
    int base = blk * 4096 + tid;
#pragma unroll
    for (int j = 0; j < 16; j++) {
        int t = base + j * 256;
        if (t < N_EDGES) {
            int d = dst[t];
            unsigned int pk = (((unsigned int)(d & 511)) << 17) | (unsigned int)src[t];
            int r = atomicAdd(&off[d >> 9], 1);
            edgeA[r] = pk;
        }
    }
}

// ===========================================================================
// passB: one block per bucket. Local hist -> dinv, local scan -> noffs,
// LDS scatter -> node-major srcs2.
// ===========================================================================
__global__ __launch_bounds__(256)
void passB_kernel(const int* __restrict__ posA, const unsigned int* __restrict__ edgeA,
                  int* __restrict__ noffs, float* __restrict__ dinv,
                  int* __restrict__ srcs2) {
    __shared__ int hist[512];
    __shared__ int off[512];
    __shared__ int ps[256];
    __shared__ int srcs_l[BCAP];

    int tid = threadIdx.x, b = blockIdx.x;
    int e0 = posA[b * EB];
    int e1 = posA[(b + 1) * EB];
    int n0 = b << 9;
    int nn = min(512, N_NODES - n0);
    int len = e1 - e0;

    hist[tid] = 0; hist[tid + 256] = 0;
    __syncthreads();
    for (int i = e0 + tid; i < e1; i += 256) atomicAdd(&hist[edgeA[i] >> 17], 1);
    __syncthreads();

    for (int n = tid; n < nn; n += 256) dinv[n0 + n] = rsqrtf((float)hist[n] + 1.0f);

    int a0 = hist[2 * tid], a1 = hist[2 * tid + 1];
    ps[tid] = a0 + a1;
    __syncthreads();
    for (int d = 1; d < 256; d <<= 1) {
        int v = (tid >= d) ? ps[tid - d] : 0;
        __syncthreads();
        ps[tid] += v;
        __syncthreads();
    }
    int pre = ps[tid] - (a0 + a1);
    off[2 * tid] = pre;
    off[2 * tid + 1] = pre + a0;
    __syncthreads();

    for (int n = tid; n < nn; n += 256) noffs[n0 + n] = e0 + off[n];
    if (b == NB - 1 && tid == 0) noffs[N_NODES] = N_EDGES;
    __syncthreads();

    if (len <= BCAP) {
        for (int i = e0 + tid; i < e1; i += 256) {
            unsigned int e = edgeA[i];
            int r = atomicAdd(&off[e >> 17], 1);
            srcs_l[r] = (int)(e & 0x1FFFFu);
        }
        __syncthreads();
        for (int i = tid; i < len; i += 256) srcs2[e0 + i] = srcs_l[i];
    } else {
        for (int i = e0 + tid; i < e1; i += 256) {
            unsigned int e = edgeA[i];
            int r = atomicAdd(&off[e >> 17], 1);
            srcs2[e0 + r] = (int)(e & 0x1FFFFu);
        }
    }
}

// ===========================================================================
// gemm1: x fp32 @ W1 -> bf16, A-fragments loaded DIRECTLY from global
// (no As LDS staging), epilogue scales by dinv[row] (pre-scaled h1 table).
// 512 threads, 128 rows/block. LDS = Wt only (17.4 KB).
// ===========================================================================
__global__ __launch_bounds__(512)
void gemm1_kernel(const float* __restrict__ X, const float* __restrict__ W,
                  const float* __restrict__ dinv, unsigned short* __restrict__ H,
                  int n_rows) {
    constexpr int K  = D_IN;
    constexpr int KP = K + 8;
    __shared__ unsigned short Wt[64 * KP];

    const int tid  = threadIdx.x;
    const int row0 = blockIdx.x * 128;

    for (int i = tid; i < K * 64; i += 512) {
        int k = i >> 6;
        int n = i & 63;
        Wt[n * KP + k] = f2bf(W[i]);
    }

    const int wave = tid >> 6;
    const int lane = tid & 63;
    const int lrow = lane & 15;
    const int quad = lane >> 4;
    const int m = wave * 16 + lrow;
    const int row = row0 + m;
    const bool valid = row < n_rows;

    // issue all 8 A-chunk loads up front (full MLP)
    float4 xa[8];
    if (valid) {
        const float4* xr4 = (const float4*)(X + (size_t)row * K);
#pragma unroll
        for (int kt = 0; kt < 4; kt++) {
            int q = (kt * 32 + quad * 8) >> 2;
            xa[2 * kt]     = xr4[q];
            xa[2 * kt + 1] = xr4[q + 1];
        }
    } else {
#pragma unroll
        for (int j = 0; j < 8; j++) xa[j] = make_float4(0.f, 0.f, 0.f, 0.f);
    }
    __syncthreads();

    f32x4 acc0 = {0.f, 0.f, 0.f, 0.f};
    f32x4 acc1 = {0.f, 0.f, 0.f, 0.f};
    f32x4 acc2 = {0.f, 0.f, 0.f, 0.f};
    f32x4 acc3 = {0.f, 0.f, 0.f, 0.f};

#pragma unroll
    for (int kt = 0; kt < 4; kt++) {
        int k0 = kt * 32 + quad * 8;
        const float* f = (const float*)&xa[2 * kt];
        bf16x8 a;
#pragma unroll
        for (int j = 0; j < 8; j++) a[j] = (short)f2bf(f[j]);
        bf16x8 b0 = *(const bf16x8*)&Wt[(0 * 16 + lrow) * KP + k0];
        bf16x8 b1 = *(const bf16x8*)&Wt[(1 * 16 + lrow) * KP + k0];
        bf16x8 b2 = *(const bf16x8*)&Wt[(2 * 16 + lrow) * KP + k0];
        bf16x8 b3 = *(const bf16x8*)&Wt[(3 * 16 + lrow) * KP + k0];
        acc0 = __builtin_amdgcn_mfma_f32_16x16x32_bf16(a, b0, acc0, 0, 0, 0);
        acc1 = __builtin_amdgcn_mfma_f32_16x16x32_bf16(a, b1, acc1, 0, 0, 0);
        acc2 = __builtin_amdgcn_mfma_f32_16x16x32_bf16(a, b2, acc2, 0, 0, 0);
        acc3 = __builtin_amdgcn_mfma_f32_16x16x32_bf16(a, b3, acc3, 0, 0, 0);
    }

    f32x4 accs[4] = {acc0, acc1, acc2, acc3};
#pragma unroll
    for (int r = 0; r < 4; r++) {
        int orow = row0 + wave * 16 + quad * 4 + r;
        if (orow < n_rows) {
            float dv = dinv[orow];
#pragma unroll
            for (int c = 0; c < 4; c++)
                H[(size_t)orow * 64 + c * 16 + lrow] = f2bf(accs[c][r] * dv);
        }
    }
}

// ---- unpack-add helpers (tables are pre-scaled by dinv[src]) ----
__device__ inline void upk_add(int4 u, float* acc) {
    unsigned int a = (unsigned int)u.x, b = (unsigned int)u.y;
    unsigned int d = (unsigned int)u.z, e = (unsigned int)u.w;
    acc[0] += __uint_as_float(a << 16);
    acc[1] += __uint_as_float(a & 0xFFFF0000u);
    acc[2] += __uint_as_float(b << 16);
    acc[3] += __uint_as_float(b & 0xFFFF0000u);
    acc[4] += __uint_as_float(d << 16);
    acc[5] += __uint_as_float(d & 0xFFFF0000u);
    acc[6] += __uint_as_float(e << 16);
    acc[7] += __uint_as_float(e & 0xFFFF0000u);
}

__device__ inline void upk8_add(int2 u, float* acc) {
    f32x2 p0 = __builtin_amdgcn_cvt_pk_f32_fp8(u.x, false);
    f32x2 p1 = __builtin_amdgcn_cvt_pk_f32_fp8(u.x, true);
    f32x2 p2 = __builtin_amdgcn_cvt_pk_f32_fp8(u.y, false);
    f32x2 p3 = __builtin_amdgcn_cvt_pk_f32_fp8(u.y, true);
    acc[0] += p0.x; acc[1] += p0.y;
    acc[2] += p1.x; acc[3] += p1.y;
    acc[4] += p2.x; acc[5] += p2.y;
    acc[6] += p3.x; acc[7] += p3.y;
}

// ===========================================================================
// FUSED gather1 + gemm2: 512 threads, 64 nodes/block, natural node order.
// Phase A: 8 lanes/node aggregate pre-scaled bf16 rows (8-deep batches with
// cross-batch src prefetch), dn*acc + b1, relu, bf16 row to LDS.
// Phase B: 8 waves MFMA 64x64x64, epilogue scales by dinv[row], stores fp8.
// ===========================================================================
__global__ __launch_bounds__(512)
void gather1_gemm2_kernel(const int* __restrict__ offs, const int* __restrict__ srcs,
                          const float* __restrict__ dinv, const unsigned short* __restrict__ h,
                          const float* __restrict__ b1v, const float* __restrict__ W2,
                          unsigned char* __restrict__ H8, int n_nodes) {
    constexpr int KP = 72;
    __shared__ unsigned short Hs[64 * KP];
    __shared__ unsigned short Wt[64 * KP];

    const int tid   = threadIdx.x;
    const int node0 = blockIdx.x * 64;

    // stage W2^T as bf16 (W2 is [64][64] row-major, in x out)
    for (int i = tid; i < 64 * 64; i += 512) {
        int k = i >> 6;
        int n = i & 63;
        Wt[n * KP + k] = f2bf(W2[i]);
    }

    // ---- phase A: gather-aggregate, 8-deep ----
    const int g    = tid >> 3;
    const int node = node0 + g;
    const int cg   = (tid & 7) * 8;

    float acc[8];
#pragma unroll
    for (int j = 0; j < 8; j++) acc[j] = 0.f;
    float dn = 0.f;

    if (node < n_nodes) {
        dn = dinv[node];
        int4 us = *(const int4*)(h + (size_t)node * 64 + cg);  // self row (pre-scaled)
        upk_add(us, acc);

        int i = offs[node];
        const int i1 = offs[node + 1];
        int rem = i1 - i;
        if (rem > 0) {
            int s[8];
#pragma unroll
            for (int j = 0; j < 8; j++) s[j] = srcs[i + (j < rem ? j : rem - 1)];
            while (rem > 0) {
                int4 u8[8];
#pragma unroll
                for (int j = 0; j < 8; j++)
                    u8[j] = *(const int4*)(h + (size_t)s[j] * 64 + cg);
                const int cur  = rem < 8 ? rem : 8;
                const int ni   = i + cur;
                const int nrem = rem - cur;
                if (nrem > 0) {
#pragma unroll
                    for (int j = 0; j < 8; j++)
                        s[j] = srcs[ni + (j < nrem ? j : nrem - 1)];
                }
#pragma unroll
                for (int j = 0; j < 8; j++) { if (j < cur) upk_add(u8[j], acc); }
                i = ni; rem = nrem;
            }
        }
    }

    // bias + relu + write LDS row (invalid nodes write relu(b1): rows unused)
    {
        float4 bv0 = *(const float4*)(b1v + cg);
        float4 bv1 = *(const float4*)(b1v + cg + 4);
        float r0 = fmaxf(dn * acc[0] + bv0.x, 0.f);
        float r1 = fmaxf(dn * acc[1] + bv0.y, 0.f);
        float r2 = fmaxf(dn * acc[2] + bv0.z, 0.f);
        float r3 = fmaxf(dn * acc[3] + bv0.w, 0.f);
        float r4 = fmaxf(dn * acc[4] + bv1.x, 0.f);
        float r5 = fmaxf(dn * acc[5] + bv1.y, 0.f);
        float r6 = fmaxf(dn * acc[6] + bv1.z, 0.f);
        float r7 = fmaxf(dn * acc[7] + bv1.w, 0.f);
        ushort4 p0 = make_ushort4(f2bf(r0), f2bf(r1), f2bf(r2), f2bf(r3));
        ushort4 p1 = make_ushort4(f2bf(r4), f2bf(r5), f2bf(r6), f2bf(r7));
        *(ushort4*)&Hs[g * KP + cg]     = p0;
        *(ushort4*)&Hs[g * KP + cg + 4] = p1;
    }
    __syncthreads();

    // ---- phase B: MFMA 64x64x64, 8 waves ----
    const int wave = tid >> 6;
    const int lane = tid & 63;
    const int lrow = lane & 15;
    const int quad = lane >> 4;
    const int rt = (wave & 3) * 16;   // row tile
    const int ct = (wave >> 2) * 32;  // col tile
    const int m = rt + lrow;

    f32x4 acc0 = {0.f, 0.f, 0.f, 0.f};
    f32x4 acc1 = {0.f, 0.f, 0.f, 0.f};
#pragma unroll
    for (int kt = 0; kt < 2; kt++) {
        int k0 = kt * 32 + quad * 8;
        bf16x8 a  = *(const bf16x8*)&Hs[m * KP + k0];
        bf16x8 w0 = *(const bf16x8*)&Wt[(ct + lrow) * KP + k0];
        bf16x8 w1 = *(const bf16x8*)&Wt[(ct + 16 + lrow) * KP + k0];
        acc0 = __builtin_amdgcn_mfma_f32_16x16x32_bf16(a, w0, acc0, 0, 0, 0);
        acc1 = __builtin_amdgcn_mfma_f32_16x16x32_bf16(a, w1, acc1, 0, 0, 0);
    }

    f32x4 accs[2] = {acc0, acc1};
#pragma unroll
    for (int r = 0; r < 4; r++) {
        int row = node0 + rt + quad * 4 + r;
        if (row < n_nodes) {
            float dv = dinv[row];
#pragma unroll
            for (int c = 0; c < 2; c++) {
                float v = accs[c][r] * dv;   // fold layer-2 dinv[src] into table
                int p = __builtin_amdgcn_cvt_pk_fp8_f32(v, v, 0, false);
                H8[(size_t)row * 64 + ct + c * 16 + lrow] = (unsigned char)(p & 0xFF);
            }
        }
    }
}

// ===========================================================================
// Gather B + POOL fused (layer 2): fp8 table PRE-SCALED by dinv[src].
// 8 lanes/node x int2, 32 nodes/block (800K threads). PING-PONG double
// buffer (measured equal to plain 8-deep; kept from r9's verified source).
// ===========================================================================
__global__ __launch_bounds__(256)
void gather_fp8_pool_kernel(const int* __restrict__ offs, const int* __restrict__ srcs,
                            const float* __restrict__ dinv, const unsigned char* __restrict__ h8,
                            const float* __restrict__ b, const int* __restrict__ batch,
                            float* __restrict__ pooled, float* __restrict__ cnt,
                            int n_nodes) {
    __shared__ float pacc[PSLOTS][64];
    __shared__ float lcnt[PSLOTS];
    __shared__ int sg[2];

    int tid = threadIdx.x;
    int node0 = blockIdx.x * 32;
    int lastn = min(node0 + 31, n_nodes - 1);
    for (int i = tid; i < PSLOTS * 64; i += 256) ((float*)pacc)[i] = 0.f;
    if (tid < PSLOTS) lcnt[tid] = 0.f;
    if (tid == 0) { sg[0] = batch[min(node0, n_nodes - 1)]; sg[1] = batch[lastn]; }
    __syncthreads();
    int g0 = sg[0];
    bool single = (sg[0] == sg[1]);   // block-uniform

    int node = node0 + (tid >> 3);
    int cg = (tid & 7) * 8;

    float r[8];
#pragma unroll
    for (int j = 0; j < 8; j++) r[j] = 0.f;

    if (node < n_nodes) {
        float dn = dinv[node];
        float acc[8];
#pragma unroll
        for (int j = 0; j < 8; j++) acc[j] = 0.f;
        {
            int2 u = *(const int2*)(h8 + (size_t)node * 64 + cg);  // self (pre-scaled)
            upk8_add(u, acc);
        }

        int i = offs[node];
        const int i1 = offs[node + 1];
        int rem = i1 - i;

        int curA = 0;
        int2 uA[8];
        if (rem > 0) {
            curA = rem < 8 ? rem : 8;
            int sA[8];
#pragma unroll
            for (int j = 0; j < 8; j++) sA[j] = srcs[i + (j < curA ? j : curA - 1)];
#pragma unroll
            for (int j = 0; j < 8; j++)
                uA[j] = *(const int2*)(h8 + (size_t)sA[j] * 64 + cg);
            i += curA; rem -= curA;
        }
        while (curA > 0) {
            int curB = 0;
            int2 uB[8];
            if (rem > 0) {
                curB = rem < 8 ? rem : 8;
                int sB[8];
#pragma unroll
                for (int j = 0; j < 8; j++) sB[j] = srcs[i + (j < curB ? j : curB - 1)];
#pragma unroll
                for (int j = 0; j < 8; j++)
                    uB[j] = *(const int2*)(h8 + (size_t)sB[j] * 64 + cg);
                i += curB; rem -= curB;
            }
            // consume A (only waits for A's 8 loads; B's stay in flight)
#pragma unroll
            for (int j = 0; j < 8; j++) { if (j < curA) upk8_add(uA[j], acc); }
#pragma unroll
            for (int j = 0; j < 8; j++) uA[j] = uB[j];
            curA = curB;
        }

        float4 b0 = *(const float4*)(b + cg);
        float4 b1 = *(const float4*)(b + cg + 4);
        r[0] = fmaxf(dn * acc[0] + b0.x, 0.f);
        r[1] = fmaxf(dn * acc[1] + b0.y, 0.f);
        r[2] = fmaxf(dn * acc[2] + b0.z, 0.f);
        r[3] = fmaxf(dn * acc[3] + b0.w, 0.f);
        r[4] = fmaxf(dn * acc[4] + b1.x, 0.f);
        r[5] = fmaxf(dn * acc[5] + b1.y, 0.f);
        r[6] = fmaxf(dn * acc[6] + b1.z, 0.f);
        r[7] = fmaxf(dn * acc[7] + b1.w, 0.f);
    }

    if (single) {
        // butterfly over lanes ^8,^16,^32: sums the 8 nodes of this wave
#pragma unroll
        for (int j = 0; j < 8; j++) {
            float v = r[j];
            v += __shfl_xor(v, 8);
            v += __shfl_xor(v, 16);
            v += __shfl_xor(v, 32);
            r[j] = v;
        }
        int wave = tid >> 6;
        int lane = tid & 63;
        if (lane < 8) {
#pragma unroll
            for (int j = 0; j < 8; j++) pacc[wave][lane * 8 + j] = r[j];
        }
        __syncthreads();
        if (tid < 64) {
            float s = pacc[0][tid] + pacc[1][tid] + pacc[2][tid] + pacc[3][tid];
            if (s != 0.f) unsafeAtomicAdd(&pooled[(size_t)g0 * 64 + tid], s);
        }
        if (tid == 0) {
            int valid = min(32, n_nodes - node0);
            unsafeAtomicAdd(&cnt[g0], (float)valid);
        }
    } else {
        if (node < n_nodes) {
            int g = batch[node];
            int slot = g - g0;          // batch sorted -> slot >= 0
            if (slot < PSLOTS) {
#pragma unroll
                for (int j = 0; j < 8; j++) atomicAdd(&pacc[slot][cg + j], r[j]);
                if ((tid & 7) == 0) atomicAdd(&lcnt[slot], 1.f);
            } else {
#pragma unroll
                for (int j = 0; j < 8; j++) unsafeAtomicAdd(&pooled[(size_t)g * 64 + cg + j], r[j]);
                if ((tid & 7) == 0) unsafeAtomicAdd(&cnt[g], 1.f);
            }
        }
        __syncthreads();
        for (int i = tid; i < PSLOTS * 64; i += 256) {
            float v = ((float*)pacc)[i];
            if (v != 0.f) unsafeAtomicAdd(&pooled[(size_t)(g0 + (i >> 6)) * 64 + (i & 63)], v);
        }
        if (tid < PSLOTS && lcnt[tid] != 0.f) unsafeAtomicAdd(&cnt[g0 + tid], lcnt[tid]);
    }
}

// ===========================================================================
// Head: pooled mean -> logits -> log_softmax.
// ===========================================================================
__global__ __launch_bounds__(256)
void head_kernel(const float* __restrict__ pooled, const float* __restrict__ cnt,
                 const float* __restrict__ Wfc, const float* __restrict__ bfc,
                 float* __restrict__ out) {
    __shared__ float Ws[HIDDEN * N_CLASSES];
    __shared__ float bs[N_CLASSES];
    int tid = threadIdx.x;
    for (int i = tid; i < HIDDEN * N_CLASSES; i += 256) Ws[i] = Wfc[i];
    if (tid < N_CLASSES) bs[tid] = bfc[tid];
    __syncthreads();

    int g = blockIdx.x * 256 + tid;
    if (g >= N_GRAPHS) return;

    float inv = 1.f / fmaxf(cnt[g], 1.f);
    float p[HIDDEN];
#pragma unroll
    for (int k = 0; k < HIDDEN; k++) p[k] = pooled[(size_t)g * 64 + k] * inv;

    float lg[N_CLASSES];
    float m = -1e30f;
#pragma unroll
    for (int j = 0; j < N_CLASSES; j++) {
        float a = bs[j];
#pragma unroll
        for (int k = 0; k < HIDDEN; k++) a += p[k] * Ws[k * N_CLASSES + j];
        lg[j] = a;
        m = fmaxf(m, a);
    }
    float s = 0.f;
#pragma unroll
    for (int j = 0; j < N_CLASSES; j++) s += __expf(lg[j] - m);
    float lse = m + __logf(s);
#pragma unroll
    for (int j = 0; j < N_CLASSES; j++) out[(size_t)g * N_CLASSES + j] = lg[j] - lse;
}

// ===========================================================================
// Launch
// ===========================================================================
extern "C" void kernel_launch(void* const* d_in, const int* in_sizes, int n_in,
                              void* d_out, int out_size, void* d_ws, size_t ws_size,
                              hipStream_t stream) {
    const float* x   = (const float*)d_in[0];
    const int*   ei  = (const int*)d_in[1];
    const int*   bat = (const int*)d_in[2];
    const float* W1  = (const float*)d_in[3];
    const float* b1  = (const float*)d_in[4];
    const float* W2  = (const float*)d_in[5];
    const float* b2  = (const float*)d_in[6];
    const float* Wfc = (const float*)d_in[7];
    const float* bfc = (const float*)d_in[8];
    float* out = (float*)d_out;

    const int* src = ei;
    const int* dst = ei + N_EDGES;

    char* ws = (char*)d_ws;

    // Layout, total ~53.8 MB:
    const size_t OFF_H     = 0;          // h1 bf16 12.8 MB (pre-scaled by dinv in gemm1)
    const size_t OFF_SRCS2 = 12800000;   // node-major srcs 6.4 MB
    const size_t OFF_NOFFS = 19200000;   // 400,016
    const size_t OFF_DINV  = 19600016;   // 400,000
    const size_t OFF_BUFB  = 25600000;   // h2 fp8 6.4 MB (pre-scaled by dinv)
    const size_t OFF_EDGEA = 38400000;   // 6.4 MB packed u32 {ldst:9|src:17} (build only)
    const size_t OFF_HA    = 51200000;   // 1,225,392
    const size_t OFF_POSA  = 52425392;   // 1,225,396 (NBE+1 ints)
    const size_t OFF_BSUM  = 53650800;   // 1,024
    const size_t OFF_POOL  = 53651824;   // 131,072
    const size_t OFF_CNT   = 53782896;   // 2,048

    unsigned short* hbuf  = (unsigned short*)(ws + OFF_H);
    int*   srcs2  = (int*)  (ws + OFF_SRCS2);
    int*   noffs  = (int*)  (ws + OFF_NOFFS);
    float* dinv   = (float*)(ws + OFF_DINV);
    unsigned char* hbuf8 = (unsigned char*)(ws + OFF_BUFB);
    unsigned int* edgeA = (unsigned int*)(ws + OFF_EDGEA);
    int*   HA     = (int*)  (ws + OFF_HA);
    int*   posA   = (int*)  (ws + OFF_POSA);
    int*   bsum   = (int*)  (ws + OFF_BSUM);
    float* pooled = (float*)(ws + OFF_POOL);
    float* cnt    = (float*)(ws + OFF_CNT);

    const int GATHER_BLOCKS = (N_NODES * 8 + 255) / 256;  // 3125 (32 nodes/block)
    const int GEMM2_BLOCKS = (N_NODES + 63) / 64;         // 1563
    const int GEMM1_BLOCKS = (N_NODES + 127) / 128;       // 782

    hipMemsetAsync(pooled, 0, (size_t)(131072 + 2048), stream);

    // 1. bucket histogram (per-edge-block counts)
    hist_kernel<<<EB, 256, 0, stream>>>(dst, HA);
    // 2. scan the (bucket, block) count matrix -> exclusive slots (2 kernels)
    scan1_kernel<<<SCB, 256, 0, stream>>>(HA, bsum, NBE);
    scan3b_kernel<<<SCB, 256, 0, stream>>>(HA, bsum, posA, NBE, SCB);
    // 3. bucket-sort edges: 4096-edge blocks, packed u32, no global atomics
    scatterA2_kernel<<<EB4, 256, 0, stream>>>(src, dst, posA, edgeA);
    // 4. per-bucket CSR build: degrees->dinv, noffs, node-major srcs2
    passB_kernel<<<NB, 256, 0, stream>>>(posA, edgeA, noffs, dinv, srcs2);
    // 5. gemm1 (direct-global A, dinv-scaled epilogue): x @ W1 -> h1 bf16
    gemm1_kernel<<<GEMM1_BLOCKS, 512, 0, stream>>>(x, W1, dinv, hbuf, N_NODES);
    // 6.+7. fused gather1 + gemm2: scaled h1 table -> h2 fp8 (pre-scaled)
    gather1_gemm2_kernel<<<GEMM2_BLOCKS, 512, 0, stream>>>(
        noffs, srcs2, dinv, hbuf, b1, W2, hbuf8, N_NODES);
    // 8. gather2 + pool fused (8 lanes/node, int2, ping-pong)
    gather_fp8_pool_kernel<<<GATHER_BLOCKS, 256, 0, stream>>>(
        noffs, srcs2, dinv, hbuf8, b2, bat, pooled, cnt, N_NODES);

    // 9. head
    head_kernel<<<(N_GRAPHS + 255) / 256, 256, 0, stream>>>(pooled, cnt, Wfc, bfc, out);
}